// Round 3
// baseline (736.804 us; speedup 1.0000x reference)
//
#include <hip/hip_runtime.h>
#include <cstddef>

constexpr int NODES = 100000;

__device__ __forceinline__ int rfl_i(int x) {
    return __builtin_amdgcn_readfirstlane(x);
}
__device__ __forceinline__ float rfl_f(float x) {
    return __int_as_float(__builtin_amdgcn_readfirstlane(__float_as_int(x)));
}

// ================= fast path: permuted-row CSR =================

__global__ __launch_bounds__(256) void count_kernel(
    const int* __restrict__ idx, int* __restrict__ cnt, int E)
{
    int i = blockIdx.x * blockDim.x + threadIdx.x;
    int stride = gridDim.x * blockDim.x;
    int e4 = E >> 2;
    const int4* idx4 = (const int4*)idx;
    for (int j = i; j < e4; j += stride) {
        int4 v = idx4[j];
        atomicAdd(&cnt[v.x], 1); atomicAdd(&cnt[v.y], 1);
        atomicAdd(&cnt[v.z], 1); atomicAdd(&cnt[v.w], 1);
    }
    for (int j = (e4 << 2) + i; j < E; j += stride) atomicAdd(&cnt[idx[j]], 1);
}

// single-block exclusive scan, 4096 elements/iter
__global__ __launch_bounds__(1024) void scan_kernel(
    const int* __restrict__ cnt, int* __restrict__ starts, int* __restrict__ cursor)
{
    __shared__ int wsum[16];
    __shared__ int running_s;
    int tid = threadIdx.x, lane = tid & 63, wv = tid >> 6;
    if (tid == 0) running_s = 0;
    __syncthreads();
    for (int base = 0; base < NODES; base += 4096) {
        int i0 = base + tid * 4;
        int c0 = 0, c1 = 0, c2 = 0, c3 = 0;
        if (i0 + 3 < NODES) {
            int4 c = *(const int4*)(cnt + i0);
            c0 = c.x; c1 = c.y; c2 = c.z; c3 = c.w;
        } else {
            if (i0     < NODES) c0 = cnt[i0];
            if (i0 + 1 < NODES) c1 = cnt[i0 + 1];
            if (i0 + 2 < NODES) c2 = cnt[i0 + 2];
            if (i0 + 3 < NODES) c3 = cnt[i0 + 3];
        }
        int t = c0 + c1 + c2 + c3;
        int x = t;
        #pragma unroll
        for (int d = 1; d < 64; d <<= 1) {
            int v = __shfl_up(x, d);
            if (lane >= d) x += v;
        }
        if (lane == 63) wsum[wv] = x;
        __syncthreads();
        if (wv == 0 && lane < 16) {
            int y = wsum[lane];
            #pragma unroll
            for (int d = 1; d < 16; d <<= 1) {
                int v = __shfl_up(y, d);
                if (lane >= d) y += v;
            }
            wsum[lane] = y;
        }
        __syncthreads();
        int woff = (wv > 0) ? wsum[wv - 1] : 0;
        int r = running_s;
        int excl = r + woff + (x - t);
        int s0 = excl, s1 = excl + c0, s2 = s1 + c1, s3 = s2 + c2;
        if (i0     < NODES) { starts[i0]     = s0; cursor[i0]     = s0; }
        if (i0 + 1 < NODES) { starts[i0 + 1] = s1; cursor[i0 + 1] = s1; }
        if (i0 + 2 < NODES) { starts[i0 + 2] = s2; cursor[i0 + 2] = s2; }
        if (i0 + 3 < NODES) { starts[i0 + 3] = s3; cursor[i0 + 3] = s3; }
        int total = wsum[15];
        __syncthreads();
        if (tid == 0) running_s = r + total;
    }
    __syncthreads();
    if (tid == 0) starts[NODES] = running_s;
}

// permute cf rows (premultiplied by w) into sorted slots; full-line stores.
// lane l: edge group g=l/4, quarter q=l%4 -> 4 lanes write one 64B line.
__global__ __launch_bounds__(256) void scatter_perm(
    const float4* __restrict__ cf4, const float* __restrict__ wts,
    const int* __restrict__ idx, int* __restrict__ cursor,
    float* __restrict__ den, float4* __restrict__ cfs4, int E)
{
    int lane = threadIdx.x & 63;
    int g = lane >> 2, q = lane & 3;
    int wid = (blockIdx.x * blockDim.x + threadIdx.x) >> 6;
    int nw = (gridDim.x * blockDim.x) >> 6;
    for (int base = wid * 16; base < E; base += nw * 16) {
        int e = base + g;
        bool valid = e < E;
        float4 v = {0.f, 0.f, 0.f, 0.f};
        float w = 0.f;
        int slot = 0;
        if (valid) {
            v = cf4[(size_t)e * 4 + q];
            w = wts[e];
            if (q == 0) {
                int n = idx[e];
                slot = atomicAdd(&cursor[n], 1);
                unsafeAtomicAdd(&den[n], w);
            }
        }
        slot = __shfl(slot, lane & ~3);
        if (valid) {
            v.x *= w; v.y *= w; v.z *= w; v.w *= w;
            cfs4[(size_t)slot * 4 + q] = v;
        }
    }
}

// stream sorted rows; one wave per node; lane = channel; fused divide
__global__ __launch_bounds__(256) void gather_stream(
    const float* __restrict__ emb, const float* __restrict__ cfs,
    const int* __restrict__ starts, const float* __restrict__ den,
    float* __restrict__ out)
{
    const int lane = threadIdx.x & 63;
    float er[16];
    #pragma unroll
    for (int f = 0; f < 16; ++f) er[f] = emb[lane * 16 + f];

    int gw = rfl_i((int)((blockIdx.x * blockDim.x + threadIdx.x) >> 6));
    int nw = (gridDim.x * blockDim.x) >> 6;

    for (int node = gw; node < NODES; node += nw) {
        int s = rfl_i(starts[node]);
        int e = rfl_i(starts[node + 1]);
        int cntn = e - s;
        const float* base = cfs + (size_t)s * 16;
        float acc = 0.f;
        int p = 0;
        int n4 = cntn & ~3;
        for (; p < n4; p += 4) {
            const float* r = base + (size_t)p * 16;
            float a0 = 0.f, a1 = 0.f, a2 = 0.f, a3 = 0.f;
            #pragma unroll
            for (int f = 0; f < 16; ++f) {
                a0 = fmaf(r[f],      er[f], a0);
                a1 = fmaf(r[16 + f], er[f], a1);
                a2 = fmaf(r[32 + f], er[f], a2);
                a3 = fmaf(r[48 + f], er[f], a3);
            }
            acc += (fmaxf(a0, 0.f) + fmaxf(a1, 0.f)) +
                   (fmaxf(a2, 0.f) + fmaxf(a3, 0.f));
        }
        for (; p < cntn; ++p) {
            const float* r = base + (size_t)p * 16;
            float a0 = 0.f;
            #pragma unroll
            for (int f = 0; f < 16; ++f) a0 = fmaf(r[f], er[f], a0);
            acc += fmaxf(a0, 0.f);
        }
        float d = rfl_f(den[node]);
        out[(size_t)node * 64 + lane] = acc / d;
    }
}

// ================= mid fallback: round-2 CSR-gather =================

__global__ __launch_bounds__(256) void scatter_kernel_fb(
    const int* __restrict__ idx, const float* __restrict__ wts,
    int* __restrict__ cursor, int* __restrict__ elist,
    float* __restrict__ welist, int E)
{
    int i = blockIdx.x * blockDim.x + threadIdx.x;
    int stride = gridDim.x * blockDim.x;
    for (; i < E; i += stride) {
        int n = idx[i];
        int slot = atomicAdd(&cursor[n], 1);
        elist[slot]  = i;
        welist[slot] = wts[i];
    }
}

__global__ __launch_bounds__(256) void gather_kernel_fb(
    const float* __restrict__ emb, const float* __restrict__ cf,
    const int* __restrict__ starts, const int* __restrict__ elist,
    const float* __restrict__ welist, float* __restrict__ out)
{
    const int lane = threadIdx.x & 63;
    float er[16];
    #pragma unroll
    for (int f = 0; f < 16; ++f) er[f] = emb[lane * 16 + f];
    int gw = rfl_i((int)((blockIdx.x * blockDim.x + threadIdx.x) >> 6));
    int nw = (gridDim.x * blockDim.x) >> 6;
    for (int node = gw; node < NODES; node += nw) {
        int s = rfl_i(starts[node]);
        int e = rfl_i(starts[node + 1]);
        float acc = 0.f, den = 0.f;
        for (int p = s; p < e; ++p) {
            int e0 = rfl_i(elist[p]);
            float w0 = rfl_f(welist[p]);
            const float* c0 = cf + (size_t)e0 * 16;
            float a0 = 0.f;
            #pragma unroll
            for (int f = 0; f < 16; ++f) a0 = fmaf(c0[f], er[f], a0);
            acc = fmaf(fmaxf(a0, 0.f), w0, acc);
            den += w0;
        }
        out[(size_t)node * 64 + lane] = acc / den;
    }
}

// ================= last fallback: atomic scatter =================

__global__ __launch_bounds__(256) void edge_scatter_fb(
    const float* __restrict__ emb, const float* __restrict__ cf,
    const float* __restrict__ wts, const int* __restrict__ idx,
    float* __restrict__ num, float* __restrict__ den, int E)
{
    const int lane = threadIdx.x & 63;
    float er[16];
    #pragma unroll
    for (int f = 0; f < 16; ++f) er[f] = emb[lane * 16 + f];
    int wid = rfl_i((int)((blockIdx.x * blockDim.x + threadIdx.x) >> 6));
    int nw = (gridDim.x * blockDim.x) >> 6;
    for (int e = wid; e < E; e += nw) {
        const float* c = cf + (size_t)e * 16;
        float a = 0.f;
        #pragma unroll
        for (int f = 0; f < 16; ++f) a = fmaf(c[f], er[f], a);
        float wv = wts[e];
        int n = idx[e];
        unsafeAtomicAdd(num + (size_t)n * 64 + lane, fmaxf(a, 0.f) * wv);
        if (lane == 0) unsafeAtomicAdd(den + n, wv);
    }
}

__global__ __launch_bounds__(256) void divide_fb(
    float* __restrict__ out, const float* __restrict__ den, int nvec)
{
    int i = blockIdx.x * blockDim.x + threadIdx.x;
    int stride = gridDim.x * blockDim.x;
    float4* o4 = reinterpret_cast<float4*>(out);
    for (; i < nvec; i += stride) {
        float4 v = o4[i];
        float d = den[i >> 4];
        v.x /= d; v.y /= d; v.z /= d; v.w /= d;
        o4[i] = v;
    }
}

extern "C" void kernel_launch(void* const* d_in, const int* in_sizes, int n_in,
                              void* d_out, int out_size, void* d_ws, size_t ws_size,
                              hipStream_t stream)
{
    const float* emb = (const float*)d_in[0];   // (64,16)
    const float* cf  = (const float*)d_in[1];   // (E,16)
    const float* wts = (const float*)d_in[2];   // (E,)
    const int*   idx = (const int*)d_in[3];     // (E,)
    int E = in_sizes[2];
    float* out = (float*)d_out;

    // fast-path layout: cnt | starts | cursor | den | cfs(E rows x 64B)
    char* wsb = (char*)d_ws;
    int* cnt    = (int*)wsb;                 // NODES
    int* starts = cnt + NODES;               // NODES+1
    int* cursor = starts + NODES + 1;        // NODES
    float* den  = (float*)(cursor + NODES);  // NODES
    size_t off = (size_t)(4 * NODES + 1) * sizeof(int);
    off = (off + 255) & ~(size_t)255;
    float* cfs = (float*)(wsb + off);
    size_t need_big = off + (size_t)E * 16 * sizeof(float);

    size_t need_csr = ((size_t)3 * NODES + 2 + 2 * (size_t)E) * sizeof(int);

    if (ws_size >= need_big) {
        hipMemsetAsync(cnt, 0, NODES * sizeof(int), stream);
        hipMemsetAsync(den, 0, NODES * sizeof(float), stream);
        count_kernel<<<1024, 256, 0, stream>>>(idx, cnt, E);
        scan_kernel<<<1, 1024, 0, stream>>>(cnt, starts, cursor);
        scatter_perm<<<2048, 256, 0, stream>>>(
            (const float4*)cf, wts, idx, cursor, den, (float4*)cfs, E);
        gather_stream<<<2048, 256, 0, stream>>>(emb, cfs, starts, den, out);
    } else if (ws_size >= need_csr) {
        int* cnt2      = (int*)d_ws;
        int* starts2   = cnt2 + NODES;
        int* cursor2   = starts2 + NODES + 1;
        int* elist     = cursor2 + NODES;
        float* welist  = (float*)(elist + E);
        hipMemsetAsync(cnt2, 0, NODES * sizeof(int), stream);
        count_kernel<<<1024, 256, 0, stream>>>(idx, cnt2, E);
        scan_kernel<<<1, 1024, 0, stream>>>(cnt2, starts2, cursor2);
        scatter_kernel_fb<<<2048, 256, 0, stream>>>(idx, wts, cursor2, elist, welist, E);
        gather_kernel_fb<<<4096, 256, 0, stream>>>(emb, cf, starts2, elist, welist, out);
    } else {
        float* den2 = (float*)d_ws;
        hipMemsetAsync(d_out, 0, (size_t)out_size * sizeof(float), stream);
        hipMemsetAsync(d_ws, 0, (size_t)NODES * sizeof(float), stream);
        edge_scatter_fb<<<4096, 256, 0, stream>>>(emb, cf, wts, idx, out, den2, E);
        divide_fb<<<2048, 256, 0, stream>>>(out, den2, out_size / 4);
    }
}